// Round 6
// baseline (406.445 us; speedup 1.0000x reference)
//
#include <hip/hip_runtime.h>
#include <hip/hip_bf16.h>

// Static problem dims
#define NS_    2
#define LQ_    1024
#define HIST_  1024
#define LK_    2048
#define NH_    32
#define NKVH_  8
#define HD_    128
#define BS_    64      // kv page size
#define BM_    128     // q rows per workgroup
#define MAXB_  32

typedef __attribute__((ext_vector_type(8))) short short8;
typedef __attribute__((ext_vector_type(4))) float f32x4;

static __device__ __forceinline__ unsigned short f2bf(float x) {
    __hip_bfloat16 h = __float2bfloat16(x);
    return *(unsigned short*)&h;
}

template<int CTRL>
static __device__ __forceinline__ float dppmax(float x) {
    int y = __builtin_amdgcn_update_dpp(0, __float_as_int(x), CTRL, 0xf, 0xf, true);
    return fmaxf(x, __int_as_float(y));
}

// Fused paged prefill attention: fp32 KV gathered + converted to bf16 in-kernel.
// Register-pipelined staging: loads(b+1) issue after staging(b), fly during compute(b).
// LDS 48 KB (K 16K + V^T 16K + P 16K), XOR-swizzled so every b128 LDS op hits
// all 32 banks (minimum 4/8-way aliasing only -> counts as conflict-free).
__global__ __launch_bounds__(256, 2)
void paged_attn(const float* __restrict__ q,
                const float* __restrict__ kc,
                const float* __restrict__ vc,
                const int* __restrict__ bt,
                float* __restrict__ out)
{
    __shared__ __align__(16) unsigned short Ksh[BS_ * HD_];   // [tok][d]   16384 B
    __shared__ __align__(16) unsigned short Vsh[HD_ * BS_];   // [d][tok]   16384 B
    __shared__ __align__(16) unsigned short Psh[BM_ * BS_];   // [row][key] 16384 B

    const int tid  = threadIdx.x;
    const int w    = tid >> 6;
    const int lane = tid & 63;
    const int n    = lane & 15;
    const int q4   = lane >> 4;

    // XCD-aware decode (gid%8 = kvh pins a KV slab per XCD L2) + balanced tile pairing
    const int gid  = blockIdx.x;           // 512
    const int kvh  = gid & 7;
    const int slot = gid >> 3;
    const int seq  = slot >> 5;
    const int sub  = slot & 31;
    const int e    = sub & 1;
    const int t3   = (sub >> 1) & 7;
    const int hp   = sub >> 4;
    const int head = kvh * 4 + hp * 2 + e;
    const int m0   = (e ? (7 - t3) : t3) * BM_;
    const int r0   = m0 + w * 32;

    // Q fragments fp32 -> bf16, pre-scaled: A[m=lane&15][k=quad*8+j]
    const float SC = 0.08838834764831845f * 1.4426950408889634f;  // 1/sqrt(128)*log2(e)
    short8 qf[2][4];
#pragma unroll
    for (int rt = 0; rt < 2; ++rt) {
        const size_t base = ((size_t)((seq * LQ_ + r0 + rt * 16 + n) * NH_ + head)) * HD_;
#pragma unroll
        for (int c = 0; c < 4; ++c) {
            float4 a = *(const float4*)(q + base + c * 32 + q4 * 8);
            float4 b = *(const float4*)(q + base + c * 32 + q4 * 8 + 4);
            unsigned short u[8] = {f2bf(a.x * SC), f2bf(a.y * SC), f2bf(a.z * SC), f2bf(a.w * SC),
                                   f2bf(b.x * SC), f2bf(b.y * SC), f2bf(b.z * SC), f2bf(b.w * SC)};
            qf[rt][c] = *(const short8*)u;
        }
    }

    f32x4 acc[2][8];
    f32x4 lf[2];
    float mrow[2][4];
#pragma unroll
    for (int rt = 0; rt < 2; ++rt) {
        lf[rt] = (f32x4){0.f, 0.f, 0.f, 0.f};
#pragma unroll
        for (int dt = 0; dt < 8; ++dt) acc[rt][dt] = (f32x4){0.f, 0.f, 0.f, 0.f};
#pragma unroll
        for (int r = 0; r < 4; ++r) mrow[rt][r] = -1e30f;
    }

    const int nb  = (HIST_ + m0 + BM_ - 1) / BS_ + 1;
    const int t8  = tid >> 5;    // 0..7
    const int q32 = tid & 31;    // 0..31
    const int* btp = bt + seq * MAXB_;

    // ---- register-pipelined fp32 staging ----
    float4 kr[8], vr[8];
    auto load_blk = [&](int b) {
        const int ph = btp[b];
        const size_t src = ((size_t)ph * BS_ * NKVH_ + kvh) * HD_;   // float elems
#pragma unroll
        for (int p = 0; p < 8; ++p)
            kr[p] = *(const float4*)(kc + src + (size_t)(p * 8 + t8) * (NKVH_ * HD_) + q32 * 4);
#pragma unroll
        for (int j = 0; j < 8; ++j)
            vr[j] = *(const float4*)(vc + src + (size_t)(t8 * 8 + j) * (NKVH_ * HD_) + q32 * 4);
    };
    auto store_blk = [&]() {
        // K[tok][d]: thread covers row p*8+t8, d-range q32*4..+4 (half of chunk q32>>1)
#pragma unroll
        for (int p = 0; p < 8; ++p) {
            const int row = p * 8 + t8;
            unsigned short u[4] = {f2bf(kr[p].x), f2bf(kr[p].y), f2bf(kr[p].z), f2bf(kr[p].w)};
            *(uint2*)&Ksh[row * HD_ + (((q32 >> 1) ^ (row & 15)) << 3) + (q32 & 1) * 4] = *(const uint2*)u;
        }
        // V^T[d][tok]: in-register 4-wide transpose; chunk swizzle folds d>>3 for bank spread
#pragma unroll
        for (int w2 = 0; w2 < 4; ++w2) {
            const int d = q32 * 4 + w2;
            unsigned short row8[8];
#pragma unroll
            for (int j = 0; j < 8; ++j) {
                float f = (w2 == 0) ? vr[j].x : (w2 == 1) ? vr[j].y : (w2 == 2) ? vr[j].z : vr[j].w;
                row8[j] = f2bf(f);
            }
            const int ch = t8 ^ (d & 7) ^ ((d >> 3) & 7);
            *(short8*)&Vsh[d * BS_ + ch * 8] = *(const short8*)row8;
        }
    };

    load_blk(0);
    short8 ones;
#pragma unroll
    for (int j = 0; j < 8; ++j) ones[j] = (short)0x3F80;

    for (int b = 0; b < nb; ++b) {
        __syncthreads();            // all waves done reading previous tiles
        store_blk();                // waits on kr/vr (issued a full compute phase ago)
        __syncthreads();            // tiles ready
        if (b + 1 < nb) load_blk(b + 1);   // in flight during compute(b)

        if (64 * b <= HIST_ + r0 + 31) {
            // ---- S = Q K^T (pre-scaled) ----
            f32x4 s[2][4];
#pragma unroll
            for (int rt = 0; rt < 2; ++rt)
#pragma unroll
                for (int kt = 0; kt < 4; ++kt) s[rt][kt] = (f32x4){0.f, 0.f, 0.f, 0.f};
#pragma unroll
            for (int kt = 0; kt < 4; ++kt) {
#pragma unroll
                for (int c = 0; c < 4; ++c) {
                    short8 kf = *(const short8*)&Ksh[(kt * 16 + n) * HD_ + (((c * 4 + q4) ^ n) << 3)];
#pragma unroll
                    for (int rt = 0; rt < 2; ++rt)
                        s[rt][kt] = __builtin_amdgcn_mfma_f32_16x16x32_bf16(qf[rt][c], kf, s[rt][kt], 0, 0, 0);
                }
            }
            const bool needMask = (64 * b + 63 > HIST_ + r0);
#pragma unroll
            for (int rt = 0; rt < 2; ++rt) {
                float mx[4], al[4];
#pragma unroll
                for (int r = 0; r < 4; ++r) mx[r] = -1e30f;
#pragma unroll
                for (int kt = 0; kt < 4; ++kt) {
#pragma unroll
                    for (int r = 0; r < 4; ++r) {
                        float t = s[rt][kt][r];
                        if (needMask) {
                            const int key = b * 64 + kt * 16 + n;
                            const int row = r0 + rt * 16 + q4 * 4 + r;
                            if (key > HIST_ + row) t = -1e30f;
                        }
                        s[rt][kt][r] = t;
                        mx[r] = fmaxf(mx[r], t);
                    }
                }
                // 16-lane row-max via DPP (VALU pipe)
#pragma unroll
                for (int r = 0; r < 4; ++r) {
                    mx[r] = dppmax<0xB1>(mx[r]);    // quad_perm xor1
                    mx[r] = dppmax<0x4E>(mx[r]);    // quad_perm xor2
                    mx[r] = dppmax<0x124>(mx[r]);   // row_ror:4
                    mx[r] = dppmax<0x128>(mx[r]);   // row_ror:8
                    const float mn = fmaxf(mrow[rt][r], mx[r]);
                    al[r] = __builtin_amdgcn_exp2f(mrow[rt][r] - mn);
                    mrow[rt][r] = mn;
                }
                // P (bf16) -> LDS, C-layout -> swizzled row-major [row][key]
                const int rbase = w * 32 + rt * 16 + q4 * 4;
#pragma unroll
                for (int kt = 0; kt < 4; ++kt) {
                    const int cb = kt * 2 + (n >> 3);
                    const int ci = n & 7;
#pragma unroll
                    for (int r = 0; r < 4; ++r) {
                        const int row = rbase + r;
                        const float p = __builtin_amdgcn_exp2f(s[rt][kt][r] - mrow[rt][r]);
                        Psh[row * BS_ + ((cb ^ (row & 7)) << 3) + ci] = f2bf(p);
                    }
                }
                if (__any(al[0] != 1.f || al[1] != 1.f || al[2] != 1.f || al[3] != 1.f)) {
#pragma unroll
                    for (int dt = 0; dt < 8; ++dt)
#pragma unroll
                        for (int r = 0; r < 4; ++r) acc[rt][dt][r] *= al[r];
#pragma unroll
                    for (int r = 0; r < 4; ++r) lf[rt][r] *= al[r];
                }
            }
            // ---- O += P V ; l += P 1 ----
#pragma unroll
            for (int ks = 0; ks < 2; ++ks) {
                short8 pa[2];
#pragma unroll
                for (int rt = 0; rt < 2; ++rt)
                    pa[rt] = *(const short8*)&Psh[(w * 32 + rt * 16 + n) * BS_ + (((ks * 4 + q4) ^ (n & 7)) << 3)];
#pragma unroll
                for (int rt = 0; rt < 2; ++rt)
                    lf[rt] = __builtin_amdgcn_mfma_f32_16x16x32_bf16(pa[rt], ones, lf[rt], 0, 0, 0);
#pragma unroll
                for (int dt = 0; dt < 8; ++dt) {
                    const int d = dt * 16 + n;
                    short8 vf = *(const short8*)&Vsh[d * BS_ + ((((ks * 4 + q4) ^ (d & 7) ^ ((d >> 3) & 7))) << 3)];
#pragma unroll
                    for (int rt = 0; rt < 2; ++rt)
                        acc[rt][dt] = __builtin_amdgcn_mfma_f32_16x16x32_bf16(pa[rt], vf, acc[rt][dt], 0, 0, 0);
                }
            }
        }
    }

    // epilogue: O = acc / l (fp32 out)
#pragma unroll
    for (int rt = 0; rt < 2; ++rt) {
        float rl[4];
#pragma unroll
        for (int r = 0; r < 4; ++r) rl[r] = 1.0f / lf[rt][r];
#pragma unroll
        for (int dt = 0; dt < 8; ++dt)
#pragma unroll
            for (int r = 0; r < 4; ++r) {
                const int row = r0 + rt * 16 + q4 * 4 + r;
                out[((size_t)((seq * LQ_ + row) * NH_ + head)) * HD_ + dt * 16 + n] = acc[rt][dt][r] * rl[r];
            }
    }
}

extern "C" void kernel_launch(void* const* d_in, const int* in_sizes, int n_in,
                              void* d_out, int out_size, void* d_ws, size_t ws_size,
                              hipStream_t stream) {
    const float* q  = (const float*)d_in[0];
    const float* kc = (const float*)d_in[1];
    const float* vc = (const float*)d_in[2];
    const int*   bt = (const int*)d_in[5];
    float*      out = (float*)d_out;
    (void)in_sizes; (void)n_in; (void)out_size; (void)d_ws; (void)ws_size;

    paged_attn<<<512, 256, 0, stream>>>(q, kc, vc, bt, out);
}

// Round 7
// 390.982 us; speedup vs baseline: 1.0395x; 1.0395x over previous
//
#include <hip/hip_runtime.h>
#include <hip/hip_bf16.h>

// Static problem dims
#define NS_    2
#define LQ_    1024
#define HIST_  1024
#define LK_    2048
#define NH_    32
#define NKVH_  8
#define HD_    128
#define BS_    64      // kv page size
#define BM_    128     // q rows per workgroup
#define MAXB_  32

typedef __attribute__((ext_vector_type(8))) short short8;
typedef __attribute__((ext_vector_type(4))) float f32x4;

#define VSTR 72   // prep-internal V transpose tile stride

static __device__ __forceinline__ unsigned short f2bf(float x) {
    __hip_bfloat16 h = __float2bfloat16(x);
    return *(unsigned short*)&h;
}

template<int CTRL>
static __device__ __forceinline__ float dppmax(float x) {
    int y = __builtin_amdgcn_update_dpp(0, __float_as_int(x), CTRL, 0xf, 0xf, true);
    return fmaxf(x, __int_as_float(y));
}

// ---------------- Pass 1: gather + fp32->bf16 + V-transpose into workspace ----------------
// Kb[grp][tok][d]  (bf16)   Vb[grp][d][tok]  (bf16, transposed); grp = seq*8+kvh
__global__ __launch_bounds__(256)
void prep_kv(const float* __restrict__ kc, const float* __restrict__ vc,
             const int* __restrict__ bt,
             unsigned short* __restrict__ Kb, unsigned short* __restrict__ Vb)
{
    __shared__ __align__(16) unsigned short Vt[HD_ * VSTR];
    const int tid = threadIdx.x;
    const int gid = blockIdx.x;            // 512 = seq(2) x kvh(8) x blk(32)
    const int seq = gid >> 8;
    const int kvh = (gid >> 5) & 7;
    const int blk = gid & 31;
    const int ph  = bt[seq * MAXB_ + blk];
    const size_t src = ((size_t)ph * BS_ * NKVH_ + kvh) * HD_;   // float elements
    const int grp = seq * NKVH_ + kvh;
    const int t8 = tid >> 5, q32 = tid & 31;

    float4 kr[8], vr[8];
#pragma unroll
    for (int p = 0; p < 8; ++p)
        kr[p] = *(const float4*)(kc + src + (size_t)(p * 8 + t8) * (NKVH_ * HD_) + q32 * 4);
#pragma unroll
    for (int j = 0; j < 8; ++j)
        vr[j] = *(const float4*)(vc + src + (size_t)(t8 * 8 + j) * (NKVH_ * HD_) + q32 * 4);

#pragma unroll
    for (int p = 0; p < 8; ++p) {
        unsigned short u[4] = {f2bf(kr[p].x), f2bf(kr[p].y), f2bf(kr[p].z), f2bf(kr[p].w)};
        *(uint2*)(Kb + ((size_t)grp * LK_ + blk * BS_ + p * 8 + t8) * HD_ + q32 * 4) = *(const uint2*)u;
    }
#pragma unroll
    for (int w2 = 0; w2 < 4; ++w2) {
        unsigned short row[8];
#pragma unroll
        for (int j = 0; j < 8; ++j) {
            float f = (w2 == 0) ? vr[j].x : (w2 == 1) ? vr[j].y : (w2 == 2) ? vr[j].z : vr[j].w;
            row[j] = f2bf(f);
        }
        *(short8*)&Vt[(q32 * 4 + w2) * VSTR + t8 * 8] = *(const short8*)row;
    }
    __syncthreads();
#pragma unroll
    for (int u = 0; u < 4; ++u) {
        const int c  = tid + 256 * u;
        const int d  = c >> 3, ch = c & 7;
        uint4 x = *(const uint4*)&Vt[d * VSTR + ch * 8];
        *(uint4*)(Vb + ((size_t)grp * HD_ + d) * LK_ + blk * BS_ + ch * 8) = x;
    }
}

// ---------------- Pass 2: fused paged prefill attention, barrier-free K-loop ----------------
// K/V MFMA B-fragments load DIRECTLY from the bf16 workspace (L2-resident, XCD-pinned)
// into registers; LDS holds only the P round-trip tile (per-wave-private rows -> no
// __syncthreads at all). One shared fbuf[16] is reused K -> V -> K to fit the unified
// 256-reg/wave budget at 2 waves/SIMD.
template<bool PREP>
__global__ __launch_bounds__(256, 2)
void paged_attn(const float* __restrict__ q,
                const unsigned short* __restrict__ Kb,
                const unsigned short* __restrict__ Vb,
                const float* __restrict__ kc,
                const float* __restrict__ vc,
                const int* __restrict__ bt,
                float* __restrict__ out)
{
    __shared__ __align__(16) unsigned short Psh[BM_ * BS_];   // 16384 B, only LDS use

    const int tid  = threadIdx.x;
    const int w    = tid >> 6;
    const int lane = tid & 63;
    const int n    = lane & 15;
    const int q4   = lane >> 4;

    // XCD-aware decode (gid%8 = kvh pins a KV slab per XCD L2) + balanced tile pairing
    const int gid  = blockIdx.x;           // 512
    const int kvh  = gid & 7;
    const int slot = gid >> 3;
    const int seq  = slot >> 5;
    const int sub  = slot & 31;
    const int e    = sub & 1;
    const int t3   = (sub >> 1) & 7;
    const int hp   = sub >> 4;
    const int head = kvh * 4 + hp * 2 + e;
    const int m0   = (e ? (7 - t3) : t3) * BM_;
    const int r0   = m0 + w * 32;
    const int grp  = seq * NKVH_ + kvh;

    // Q fragments fp32 -> bf16 (RNE), pre-scaled: A[m=lane&15][k=quad*8+j]
    const float SC = 0.08838834764831845f * 1.4426950408889634f;  // 1/sqrt(128)*log2(e)
    short8 qf[2][4];
#pragma unroll
    for (int rt = 0; rt < 2; ++rt) {
        const size_t base = ((size_t)((seq * LQ_ + r0 + rt * 16 + n) * NH_ + head)) * HD_;
#pragma unroll
        for (int c = 0; c < 4; ++c) {
            float4 a = *(const float4*)(q + base + c * 32 + q4 * 8);
            float4 b = *(const float4*)(q + base + c * 32 + q4 * 8 + 4);
            unsigned short u[8] = {f2bf(a.x * SC), f2bf(a.y * SC), f2bf(a.z * SC), f2bf(a.w * SC),
                                   f2bf(b.x * SC), f2bf(b.y * SC), f2bf(b.z * SC), f2bf(b.w * SC)};
            qf[rt][c] = *(const short8*)u;
        }
    }

    f32x4 acc[2][8];
    f32x4 lf[2];
    float mrow[2][4];
#pragma unroll
    for (int rt = 0; rt < 2; ++rt) {
        lf[rt] = (f32x4){0.f, 0.f, 0.f, 0.f};
#pragma unroll
        for (int dt = 0; dt < 8; ++dt) acc[rt][dt] = (f32x4){0.f, 0.f, 0.f, 0.f};
#pragma unroll
        for (int r = 0; r < 4; ++r) mrow[rt][r] = -1e30f;
    }

    // per-wave block count (no WG coupling; waves fully independent)
    const int nb_w = ((HIST_ + r0 + 31) >> 6) + 1;
    const unsigned short* kSrc = Kb + (size_t)grp * LK_ * HD_;
    const unsigned short* vSrc = Vb + (size_t)grp * HD_ * LK_;
    const int* btp = bt + seq * MAXB_;

    short8 fbuf[16];   // shared K/V fragment buffer (reused K -> V -> K)

    auto loadK = [&](int b) {
        if constexpr (PREP) {
            const unsigned short* base = kSrc + (size_t)b * BS_ * HD_ + n * HD_ + q4 * 8;
#pragma unroll
            for (int kt = 0; kt < 4; ++kt)
#pragma unroll
                for (int c = 0; c < 4; ++c)
                    fbuf[kt * 4 + c] = *(const short8*)(base + kt * 16 * HD_ + c * 32);
        } else {
            const int ph = btp[b];
            const size_t src = ((size_t)ph * BS_ * NKVH_ + kvh) * HD_;
#pragma unroll
            for (int kt = 0; kt < 4; ++kt)
#pragma unroll
                for (int c = 0; c < 4; ++c) {
                    const float* p4 = kc + src + (size_t)(kt * 16 + n) * (NKVH_ * HD_) + c * 32 + q4 * 8;
                    float4 a = *(const float4*)p4;
                    float4 d = *(const float4*)(p4 + 4);
                    unsigned short u[8] = {f2bf(a.x), f2bf(a.y), f2bf(a.z), f2bf(a.w),
                                           f2bf(d.x), f2bf(d.y), f2bf(d.z), f2bf(d.w)};
                    fbuf[kt * 4 + c] = *(const short8*)u;
                }
        }
    };
    auto loadV = [&](int b) {
        if constexpr (PREP) {
            const unsigned short* base = vSrc + (size_t)n * LK_ + b * BS_ + q4 * 8;
#pragma unroll
            for (int ks = 0; ks < 2; ++ks)
#pragma unroll
                for (int dt = 0; dt < 8; ++dt)
                    fbuf[ks * 8 + dt] = *(const short8*)(base + (size_t)dt * 16 * LK_ + ks * 32);
        } else {
            const int ph = btp[b];
            const size_t src = ((size_t)ph * BS_ * NKVH_ + kvh) * HD_;
#pragma unroll
            for (int ks = 0; ks < 2; ++ks)
#pragma unroll
                for (int dt = 0; dt < 8; ++dt) {
                    unsigned short u[8];
#pragma unroll
                    for (int j = 0; j < 8; ++j)
                        u[j] = f2bf(vc[src + (size_t)(ks * 32 + q4 * 8 + j) * (NKVH_ * HD_) + dt * 16 + n]);
                    fbuf[ks * 8 + dt] = *(const short8*)u;
                }
        }
    };

    loadK(0);
    short8 ones;
#pragma unroll
    for (int j = 0; j < 8; ++j) ones[j] = (short)0x3F80;

    for (int b = 0; b < nb_w; ++b) {
        // ---- S = Q K^T (K frags in fbuf) ----
        f32x4 s[2][4];
#pragma unroll
        for (int rt = 0; rt < 2; ++rt)
#pragma unroll
            for (int kt = 0; kt < 4; ++kt) s[rt][kt] = (f32x4){0.f, 0.f, 0.f, 0.f};
#pragma unroll
        for (int kt = 0; kt < 4; ++kt)
#pragma unroll
            for (int c = 0; c < 4; ++c) {
                const short8 kf = fbuf[kt * 4 + c];
#pragma unroll
                for (int rt = 0; rt < 2; ++rt)
                    s[rt][kt] = __builtin_amdgcn_mfma_f32_16x16x32_bf16(qf[rt][c], kf, s[rt][kt], 0, 0, 0);
            }
        loadV(b);   // overwrites fbuf after QK consumed it; in flight during softmax

        const bool needMask = (64 * b + 63 > HIST_ + r0);
#pragma unroll
        for (int rt = 0; rt < 2; ++rt) {
            float mx[4], al[4];
#pragma unroll
            for (int r = 0; r < 4; ++r) mx[r] = -1e30f;
#pragma unroll
            for (int kt = 0; kt < 4; ++kt)
#pragma unroll
                for (int r = 0; r < 4; ++r) {
                    float t = s[rt][kt][r];
                    if (needMask) {
                        const int key = b * 64 + kt * 16 + n;
                        const int row = r0 + rt * 16 + q4 * 4 + r;
                        if (key > HIST_ + row) t = -1e30f;
                    }
                    s[rt][kt][r] = t;
                    mx[r] = fmaxf(mx[r], t);
                }
#pragma unroll
            for (int r = 0; r < 4; ++r) {
                mx[r] = dppmax<0xB1>(mx[r]);    // quad_perm xor1
                mx[r] = dppmax<0x4E>(mx[r]);    // quad_perm xor2
                mx[r] = dppmax<0x124>(mx[r]);   // row_ror:4
                mx[r] = dppmax<0x128>(mx[r]);   // row_ror:8
                const float mn = fmaxf(mrow[rt][r], mx[r]);
                al[r] = __builtin_amdgcn_exp2f(mrow[rt][r] - mn);
                mrow[rt][r] = mn;
            }
            // P -> LDS (truncating bf16 pack: 1 lshr, P in [0,1]); R5-measured conflict-free swizzle
            const int rbase = w * 32 + rt * 16 + q4 * 4;
#pragma unroll
            for (int kt = 0; kt < 4; ++kt) {
                const int cb = kt * 2 + (n >> 3);
                const int ci = n & 7;
#pragma unroll
                for (int r = 0; r < 4; ++r) {
                    const int row = rbase + r;
                    const float p = __builtin_amdgcn_exp2f(s[rt][kt][r] - mrow[rt][r]);
                    Psh[row * BS_ + ((cb ^ (row & 7)) << 3) + ci] =
                        (unsigned short)(__float_as_uint(p) >> 16);
                }
            }
            if (__any(al[0] != 1.f || al[1] != 1.f || al[2] != 1.f || al[3] != 1.f)) {
#pragma unroll
                for (int dt = 0; dt < 8; ++dt)
#pragma unroll
                    for (int r = 0; r < 4; ++r) acc[rt][dt][r] *= al[r];
#pragma unroll
                for (int r = 0; r < 4; ++r) lf[rt][r] *= al[r];
            }
        }
        // ---- O += P V ; l += P 1  (V frags in fbuf; P read back per-wave, no barrier) ----
#pragma unroll
        for (int ks = 0; ks < 2; ++ks) {
            short8 pa[2];
#pragma unroll
            for (int rt = 0; rt < 2; ++rt)
                pa[rt] = *(const short8*)&Psh[(w * 32 + rt * 16 + n) * BS_ + (((ks * 4 + q4) ^ (n & 7)) << 3)];
#pragma unroll
            for (int rt = 0; rt < 2; ++rt)
                lf[rt] = __builtin_amdgcn_mfma_f32_16x16x32_bf16(pa[rt], ones, lf[rt], 0, 0, 0);
#pragma unroll
            for (int dt = 0; dt < 8; ++dt) {
                const short8 vf = fbuf[ks * 8 + dt];
#pragma unroll
                for (int rt = 0; rt < 2; ++rt)
                    acc[rt][dt] = __builtin_amdgcn_mfma_f32_16x16x32_bf16(pa[rt], vf, acc[rt][dt], 0, 0, 0);
            }
        }
        if (b + 1 < nb_w) loadK(b + 1);   // refill fbuf for next QK
    }

    // epilogue: O = acc / l (fp32 out)
#pragma unroll
    for (int rt = 0; rt < 2; ++rt) {
        float rl[4];
#pragma unroll
        for (int r = 0; r < 4; ++r) rl[r] = 1.0f / lf[rt][r];
#pragma unroll
        for (int dt = 0; dt < 8; ++dt)
#pragma unroll
            for (int r = 0; r < 4; ++r) {
                const int row = r0 + rt * 16 + q4 * 4 + r;
                out[((size_t)((seq * LQ_ + row) * NH_ + head)) * HD_ + dt * 16 + n] = acc[rt][dt][r] * rl[r];
            }
    }
}

extern "C" void kernel_launch(void* const* d_in, const int* in_sizes, int n_in,
                              void* d_out, int out_size, void* d_ws, size_t ws_size,
                              hipStream_t stream) {
    const float* q  = (const float*)d_in[0];
    const float* kc = (const float*)d_in[1];
    const float* vc = (const float*)d_in[2];
    const int*   bt = (const int*)d_in[5];
    float*      out = (float*)d_out;
    (void)in_sizes; (void)n_in; (void)out_size;

    const size_t kb_elems = (size_t)NS_ * NKVH_ * LK_ * HD_;        // 4.19M
    const size_t need = kb_elems * 2 * sizeof(unsigned short);      // 16.78 MB
    if (ws_size >= need) {
        unsigned short* Kb = (unsigned short*)d_ws;
        unsigned short* Vb = Kb + kb_elems;
        prep_kv<<<512, 256, 0, stream>>>(kc, vc, bt, Kb, Vb);
        paged_attn<true><<<512, 256, 0, stream>>>(q, Kb, Vb, kc, vc, bt, out);
    } else {
        paged_attn<false><<<512, 256, 0, stream>>>(q, nullptr, nullptr, kc, vc, bt, out);
    }
}